// Round 2
// baseline (826.518 us; speedup 1.0000x reference)
//
#include <hip/hip_runtime.h>

typedef unsigned short u16;
typedef __attribute__((ext_vector_type(8))) short bf16x8;
typedef __attribute__((ext_vector_type(4))) float f32x4;

#define L_ 512
#define D_ 128
#define LL_ (512*512)
#define LP_ 136   // LDS pitch for 128-wide rows (16B-aligned)
#define TP_ 72    // LDS pitch for 64-wide rows

// workspace (u16 elements): wt | bias2(f32) | a_t | b_tt | k_t
#define WT_OFF 0
#define B2_OFF 98304            // 768 f32 = 1536 u16
#define AT_OFF (B2_OFF + 1536)
#define BT_OFF (AT_OFF + 128*LL_)
#define KT_OFF (BT_OFF + 128*LL_)

union U16x8 { uint4 u4; bf16x8 v; u16 s[8]; };
union U16x4 { ushort4 v; u16 s[4]; };

__device__ __forceinline__ u16 f2bf(float f){
  union { float f; unsigned int i; } w; w.f = f;
  unsigned int r = w.i + 0x7FFFu + ((w.i >> 16) & 1u);  // RNE
  return (u16)(r >> 16);
}
__device__ __forceinline__ float sigm(float x){
  return 1.0f / (1.0f + __expf(-x));
}

// prep: wt[w][n][k] = W_w[k][n] * lnscale[k] (bf16), and
// bias2[w][n] = b_w[n] + sum_k lnbias[k] * W_w[k][n] (f32).
// blocks 0..383: wt elements; blocks 384..386: bias2 (768 outputs).
__global__ __launch_bounds__(256) void conv_kernel(
    const float* __restrict__ Wga, const float* __restrict__ Wla,
    const float* __restrict__ Wgb, const float* __restrict__ Wlb,
    const float* __restrict__ Wgo, const float* __restrict__ Wlo,
    const float* __restrict__ lnw, const float* __restrict__ lnb,
    const float* __restrict__ onw, const float* __restrict__ onb,
    const float* __restrict__ bga, const float* __restrict__ bla,
    const float* __restrict__ bgb, const float* __restrict__ blb,
    const float* __restrict__ bgo, const float* __restrict__ blo,
    u16* __restrict__ wt, float* __restrict__ bias2)
{
  if (blockIdx.x < 384){
    int idx = blockIdx.x*256 + threadIdx.x;            // 0..98303
    int w = idx >> 14, rem = idx & 16383, n = rem >> 7, k = rem & 127;
    const float* src;
    switch (w){
      case 0: src = Wga; break; case 1: src = Wla; break; case 2: src = Wgb; break;
      case 3: src = Wlb; break; case 4: src = Wgo; break; default: src = Wlo;
    }
    float sc = (w == 5) ? onw[k] : lnw[k];
    wt[idx] = f2bf(src[k*128 + n] * sc);
  } else {
    int j = (blockIdx.x - 384)*256 + threadIdx.x;      // 0..767
    int w = j >> 7, n = j & 127;
    const float* src; const float* bs;
    switch (w){
      case 0: src = Wga; bs = bga; break; case 1: src = Wla; bs = bla; break;
      case 2: src = Wgb; bs = bgb; break; case 3: src = Wlb; bs = blb; break;
      case 4: src = Wgo; bs = bgo; break; default: src = Wlo; bs = blo;
    }
    const float* lb = (w == 5) ? onb : lnb;
    float acc = bs[n];
    for (int k = 0; k < 128; ++k) acc += lb[k] * src[k*128 + n];
    bias2[j] = acc;
  }
}

// C[128x128] += A_lds[128xK=128 (pitch LP_)] * B  (wtm is [N=128][K=128] bf16)
__device__ __forceinline__ void gemm128(const u16* znlds, const u16* __restrict__ wtm,
                                        int wm, int wn, int quad, int l16, f32x4 acc[4][4])
{
  bf16x8 bf[4][4];
#pragma unroll
  for (int nt = 0; nt < 4; ++nt){
    int n = wn*64 + nt*16 + l16;
#pragma unroll
    for (int kc = 0; kc < 4; ++kc){
      U16x8 u; u.u4 = *(const uint4*)(wtm + n*128 + kc*32 + quad*8);
      bf[nt][kc] = u.v;
    }
  }
#pragma unroll
  for (int mt = 0; mt < 4; ++mt){
    int row = wm*64 + mt*16 + l16;
    bf16x8 af[4];
#pragma unroll
    for (int kc = 0; kc < 4; ++kc)
      af[kc] = *(const bf16x8*)(znlds + row*LP_ + kc*32 + quad*8);
#pragma unroll
    for (int nt = 0; nt < 4; ++nt)
#pragma unroll
      for (int kc = 0; kc < 4; ++kc)
        acc[mt][nt] = __builtin_amdgcn_mfma_f32_16x16x32_bf16(af[kc], bf[nt][kc], acc[mt][nt], 0, 0, 0);
  }
}

// 64-row variant: C[64x128] += A_lds[64x128 (pitch LP_)] * B
__device__ __forceinline__ void gemm64(const u16* alds, const u16* __restrict__ wtm,
                                       int wm, int wn, int quad, int l16, f32x4 acc[2][4])
{
  bf16x8 bf[4][4];
#pragma unroll
  for (int nt = 0; nt < 4; ++nt){
    int n = wn*64 + nt*16 + l16;
#pragma unroll
    for (int kc = 0; kc < 4; ++kc){
      U16x8 u; u.u4 = *(const uint4*)(wtm + n*128 + kc*32 + quad*8);
      bf[nt][kc] = u.v;
    }
  }
#pragma unroll
  for (int mt = 0; mt < 2; ++mt){
    int row = wm*32 + mt*16 + l16;
    bf16x8 af[4];
#pragma unroll
    for (int kc = 0; kc < 4; ++kc)
      af[kc] = *(const bf16x8*)(alds + row*LP_ + kc*32 + quad*8);
#pragma unroll
    for (int nt = 0; nt < 4; ++nt)
#pragma unroll
      for (int kc = 0; kc < 4; ++kc)
        acc[mt][nt] = __builtin_amdgcn_mfma_f32_16x16x32_bf16(af[kc], bf[nt][kc], acc[mt][nt], 0, 0, 0);
  }
}

// type0 blocks (bid<2048): row tiles (fixed i)   -> a_t[c][i][m]
// type1 blocks:            column tiles (fixed j) -> b_tt[c][j][m]
// LN affine folded into wt/bias2; zn and trh share one LDS buffer (35 KB -> 4 blocks/CU).
__global__ __launch_bounds__(256, 4) void stageA_kernel(
    const float* __restrict__ z, const u16* __restrict__ wt,
    const float* __restrict__ bias2,
    u16* __restrict__ a_t, u16* __restrict__ b_tt)
{
  __shared__ __align__(16) u16 smem[128*LP_];   // zn during gemms, trh afterwards
  u16* zn = smem;
  u16* trh = smem;

  const int bid = blockIdx.x;
  const int type = bid >> 11;
  const int tile = bid & 2047;
  const int outer = tile >> 2;   // i (type0) or j (type1)
  const int seg = tile & 3;

  const int t = threadIdx.x;
  const int r = t >> 1, h = t & 1;
  const int lane = t & 63, wave = t >> 6;
  const int quad = lane >> 4, l16 = lane & 15;
  const int wm = wave & 1, wn = wave >> 1;

  { // ---- LayerNorm (f32, no affine) of 128 z-rows into zn LDS (bf16) ----
    int gpos = (type == 0) ? (outer*L_ + seg*128 + r) : ((seg*128 + r)*L_ + outer);
    const float* zrow = z + gpos*D_ + h*64;
    float raw[64];
    float sum = 0.f, sq = 0.f;
#pragma unroll
    for (int q = 0; q < 16; ++q){
      float4 v = *(const float4*)(zrow + q*4);
      raw[q*4+0] = v.x; raw[q*4+1] = v.y; raw[q*4+2] = v.z; raw[q*4+3] = v.w;
      sum += v.x + v.y + v.z + v.w;
      sq  += v.x*v.x + v.y*v.y + v.z*v.z + v.w*v.w;
    }
    sum += __shfl_xor(sum, 1, 64);
    sq  += __shfl_xor(sq , 1, 64);
    float mu = sum * (1.f/128.f);
    float rstd = rsqrtf(sq*(1.f/128.f) - mu*mu + 1e-5f);
#pragma unroll
    for (int q = 0; q < 8; ++q){
      U16x8 o;
#pragma unroll
      for (int e = 0; e < 8; ++e)
        o.s[e] = f2bf((raw[q*8+e] - mu)*rstd);
      *(uint4*)(zn + r*LP_ + h*64 + q*8) = o.u4;
    }
  }
  __syncthreads();

  const u16* wg   = wt + (type ? 2 : 0)*16384;
  const u16* wl   = wt + (type ? 3 : 1)*16384;
  const float* bgp = bias2 + (type ? 2 : 0)*128;
  const float* blp = bias2 + (type ? 3 : 1)*128;
  const f32x4 z4 = {0.f, 0.f, 0.f, 0.f};

  f32x4 accG[4][4], accL[4][4];
#pragma unroll
  for (int mt = 0; mt < 4; ++mt)
#pragma unroll
    for (int nt = 0; nt < 4; ++nt){ accG[mt][nt] = z4; accL[mt][nt] = z4; }

  gemm128(zn, wg, wm, wn, quad, l16, accG);
#pragma unroll
  for (int nt = 0; nt < 4; ++nt){
    float bb = bgp[wn*64 + nt*16 + l16];
#pragma unroll
    for (int mt = 0; mt < 4; ++mt)
#pragma unroll
      for (int e = 0; e < 4; ++e)
        accG[mt][nt][e] = sigm(accG[mt][nt][e] + bb);
  }
  gemm128(zn, wl, wm, wn, quad, l16, accL);
#pragma unroll
  for (int nt = 0; nt < 4; ++nt){
    float bb = blp[wn*64 + nt*16 + l16];
#pragma unroll
    for (int mt = 0; mt < 4; ++mt)
#pragma unroll
      for (int e = 0; e < 4; ++e)
        accG[mt][nt][e] *= (accL[mt][nt][e] + bb);   // gated product in accG
  }

  __syncthreads();   // zn dead; trh may now overwrite the same LDS

  // ---- transpose-store product channel-major (wave-row split, 2 passes) ----
  u16* dst = type ? b_tt : a_t;
  const int base = outer*L_ + seg*128;
#pragma unroll
  for (int pass = 0; pass < 2; ++pass){
    if (wm == pass){
#pragma unroll
      for (int nt = 0; nt < 4; ++nt){
        int gcol = wn*64 + nt*16 + l16;
#pragma unroll
        for (int mt = 0; mt < 4; ++mt){
          U16x4 pk;
#pragma unroll
          for (int e = 0; e < 4; ++e)
            pk.s[e] = f2bf(accG[mt][nt][e]);
          *(ushort4*)(trh + gcol*TP_ + mt*16 + quad*4) = pk.v;
        }
      }
    }
    __syncthreads();
#pragma unroll
    for (int q = 0; q < 4; ++q){
      uint4 v = *(const uint4*)(trh + r*TP_ + h*32 + q*8);
      *(uint4*)(dst + r*LL_ + base + pass*64 + h*32 + q*8) = v;
    }
    __syncthreads();
  }
}

// k_t[c][i][j] = sum_m a_t[c][i][m] * b_tt[c][j][m]
// single-buffer 32 KB (4 blocks/CU), global_load_lds w16 + XOR swizzle, XCD-swizzled grid.
__global__ __launch_bounds__(256, 4) void stageT_kernel(
    const u16* __restrict__ a_t, const u16* __restrict__ b_tt, u16* __restrict__ k_t)
{
  __shared__ __align__(16) u16 As[128*64];   // 16 KiB
  __shared__ __align__(16) u16 Bs[128*64];   // 16 KiB
  const int bid = blockIdx.x;                 // 2048 = 8 * 256
  const int lid = (bid & 7)*256 + (bid >> 3); // XCD k owns 16 whole channels (4 MB = L2)
  const int c = lid >> 4, it = (lid >> 2) & 3, jt = lid & 3;
  const u16* Ab = a_t + c*LL_ + it*128*L_;
  const u16* Bb = b_tt + c*LL_ + jt*128*L_;
  const int t = threadIdx.x;
  const int lane = t & 63, wave = t >> 6;
  const int quad = lane >> 4, l16 = lane & 15;
  const int wm = wave & 1, wn = wave >> 1;
  const int sr8 = lane >> 3, scl = lane & 7;
  const int cgx = scl ^ sr8;                  // pre-swizzled source chunk (row&7 == sr8)
  const int swz = (l16 & 7) << 3;             // read-side XOR in u16 units (row&7 == l16&7)

  f32x4 acc[4][4];
  const f32x4 z4 = {0.f,0.f,0.f,0.f};
#pragma unroll
  for (int mt = 0; mt < 4; ++mt)
#pragma unroll
    for (int nt = 0; nt < 4; ++nt) acc[mt][nt] = z4;

  for (int kt = 0; kt < 8; ++kt){
    const int k0 = kt*64;
    // stage: LDS[row][cl] = G[row][cl ^ (row&7)] (involution; read applies same XOR)
#pragma unroll
    for (int q = 0; q < 4; ++q){
      int row = q*32 + wave*8 + sr8;
      __builtin_amdgcn_global_load_lds(
          (const __attribute__((address_space(1))) void*)(Ab + row*L_ + k0 + cgx*8),
          (__attribute__((address_space(3))) void*)(&As[(q*32 + wave*8)*64]),
          16, 0, 0);
    }
#pragma unroll
    for (int q = 0; q < 4; ++q){
      int row = q*32 + wave*8 + sr8;
      __builtin_amdgcn_global_load_lds(
          (const __attribute__((address_space(1))) void*)(Bb + row*L_ + k0 + cgx*8),
          (__attribute__((address_space(3))) void*)(&Bs[(q*32 + wave*8)*64]),
          16, 0, 0);
    }
    __syncthreads();   // compiler drains vmcnt before barrier -> tile resident
    bf16x8 bfr[4][2];
#pragma unroll
    for (int nt = 0; nt < 4; ++nt){
      int brow = wn*64 + nt*16 + l16;
#pragma unroll
      for (int ks = 0; ks < 2; ++ks)
        bfr[nt][ks] = *(const bf16x8*)(Bs + brow*64 + (((ks*4 + quad)*8) ^ swz));
    }
#pragma unroll
    for (int mt = 0; mt < 4; ++mt){
      int arow = wm*64 + mt*16 + l16;
      bf16x8 af[2];
#pragma unroll
      for (int ks = 0; ks < 2; ++ks)
        af[ks] = *(const bf16x8*)(As + arow*64 + (((ks*4 + quad)*8) ^ swz));
#pragma unroll
      for (int nt = 0; nt < 4; ++nt)
#pragma unroll
        for (int ks = 0; ks < 2; ++ks)
          acc[mt][nt] = __builtin_amdgcn_mfma_f32_16x16x32_bf16(af[ks], bfr[nt][ks], acc[mt][nt], 0, 0, 0);
    }
    __syncthreads();   // all reads done before next tile overwrites
  }

#pragma unroll
  for (int mt = 0; mt < 4; ++mt)
#pragma unroll
    for (int nt = 0; nt < 4; ++nt){
      int gcol = wn*64 + nt*16 + l16;
#pragma unroll
      for (int e = 0; e < 4; ++e){
        int grow = wm*64 + mt*16 + quad*4 + e;
        k_t[c*LL_ + (it*128 + grow)*L_ + jt*128 + gcol] = f2bf(acc[mt][nt][e]);
      }
    }
}

// out[pos][d] = sigmoid(LN(z)[pos]@Wgo' + bgo') * (LN_c(k)[pos]@Wlo' + blo'), f32 out
// kl and znp alias one LDS buffer (36 KB total -> 4 blocks/CU); LN affine folded.
__global__ __launch_bounds__(256, 4) void stageC_kernel(
    const u16* __restrict__ k_t, const float* __restrict__ z,
    const u16* __restrict__ wt, const float* __restrict__ bias2,
    float* __restrict__ out)
{
  __shared__ __align__(16) u16 zn2[64*LP_];    // LN_c(k) [j][c]  (17 KB)
  __shared__ __align__(16) u16 kbuf[128*TP_];  // k tile, later LN(z) [pos][c] (18 KB)
  const u16* wtgo = wt + 4*16384;
  const u16* wtlo = wt + 5*16384;
  const float* bgo2 = bias2 + 4*128;
  const float* blo2 = bias2 + 5*128;
  const int bx = blockIdx.x;
  const int pos0 = (bx >> 3)*L_ + (bx & 7)*64;
  const int t = threadIdx.x, r = t >> 1, h = t & 1;
  const int rl4 = t >> 2, qd = t & 3;
  const int lane = t & 63, wave = t >> 6;
  const int quad = lane >> 4, l16 = lane & 15;
  const int wm = wave & 1, wn = wave >> 1;

  // phase 0: stage k tile [c][64 j]
#pragma unroll
  for (int q = 0; q < 4; ++q)
    *(uint4*)(kbuf + r*TP_ + h*32 + q*8) = *(const uint4*)(k_t + r*LL_ + pos0 + h*32 + q*8);
  __syncthreads();

  { // phase 1: zn2 = LN over channels of k for column j=rl4 (4 threads/column via qd)
    float sum = 0.f, sq = 0.f;
    float kv[32];
#pragma unroll
    for (int q = 0; q < 32; ++q){
      union { unsigned int i; float f; } w;
      w.i = ((unsigned int)kbuf[(qd*32 + q)*TP_ + rl4]) << 16;
      kv[q] = w.f; sum += w.f; sq += w.f*w.f;
    }
    sum += __shfl_xor(sum, 1, 64); sq += __shfl_xor(sq, 1, 64);
    sum += __shfl_xor(sum, 2, 64); sq += __shfl_xor(sq, 2, 64);
    float mu = sum*(1.f/128.f);
    float rstd = rsqrtf(sq*(1.f/128.f) - mu*mu + 1e-5f);
#pragma unroll
    for (int q = 0; q < 4; ++q){
      U16x8 o;
#pragma unroll
      for (int e = 0; e < 8; ++e)
        o.s[e] = f2bf((kv[q*8+e] - mu)*rstd);
      *(uint4*)(zn2 + rl4*LP_ + qd*32 + q*8) = o.u4;
    }
  }
  __syncthreads();   // kbuf (k tile) dead; reuse for LN(z)

  { // phase 2: kbuf = LN(z) row pos0+rl4 (4 threads/position via qd), f32 source
    const float* zr = z + (pos0 + rl4)*D_ + qd*32;
    float zv[32];
    float sum = 0.f, sq = 0.f;
#pragma unroll
    for (int q = 0; q < 8; ++q){
      float4 v = *(const float4*)(zr + q*4);
      zv[q*4+0] = v.x; zv[q*4+1] = v.y; zv[q*4+2] = v.z; zv[q*4+3] = v.w;
      sum += v.x + v.y + v.z + v.w;
      sq  += v.x*v.x + v.y*v.y + v.z*v.z + v.w*v.w;
    }
    sum += __shfl_xor(sum, 1, 64); sq += __shfl_xor(sq, 1, 64);
    sum += __shfl_xor(sum, 2, 64); sq += __shfl_xor(sq, 2, 64);
    float mu = sum*(1.f/128.f);
    float rstd = rsqrtf(sq*(1.f/128.f) - mu*mu + 1e-5f);
#pragma unroll
    for (int q = 0; q < 4; ++q){
      U16x8 o;
#pragma unroll
      for (int e = 0; e < 8; ++e)
        o.s[e] = f2bf((zv[q*8+e] - mu)*rstd);
      *(uint4*)(kbuf + rl4*LP_ + qd*32 + q*8) = o.u4;
    }
  }
  __syncthreads();

  f32x4 accK[2][4], accO[2][4];
  const f32x4 z4 = {0.f,0.f,0.f,0.f};
#pragma unroll
  for (int mt = 0; mt < 2; ++mt)
#pragma unroll
    for (int nt = 0; nt < 4; ++nt){ accK[mt][nt] = z4; accO[mt][nt] = z4; }

  gemm64(zn2,  wtlo, wm, wn, quad, l16, accK);
  gemm64(kbuf, wtgo, wm, wn, quad, l16, accO);

#pragma unroll
  for (int nt = 0; nt < 4; ++nt){
    int gcol = wn*64 + nt*16 + l16;
    float bo = bgo2[gcol], bl = blo2[gcol];
#pragma unroll
    for (int mt = 0; mt < 2; ++mt)
#pragma unroll
      for (int e = 0; e < 4; ++e){
        int grow = wm*32 + mt*16 + quad*4 + e;
        float s = sigm(accO[mt][nt][e] + bo);
        out[(pos0 + grow)*D_ + gcol] = s*(accK[mt][nt][e] + bl);
      }
  }
}

extern "C" void kernel_launch(void* const* d_in, const int* in_sizes, int n_in,
                              void* d_out, int out_size, void* d_ws, size_t ws_size,
                              hipStream_t stream)
{
  const float* z   = (const float*)d_in[0];
  const float* lnw = (const float*)d_in[1];
  const float* lnb = (const float*)d_in[2];
  const float* Wga = (const float*)d_in[3];
  const float* bga = (const float*)d_in[4];
  const float* Wla = (const float*)d_in[5];
  const float* bla = (const float*)d_in[6];
  const float* Wgb = (const float*)d_in[7];
  const float* bgb = (const float*)d_in[8];
  const float* Wlb = (const float*)d_in[9];
  const float* blb = (const float*)d_in[10];
  const float* onw = (const float*)d_in[11];
  const float* onb = (const float*)d_in[12];
  const float* Wgo = (const float*)d_in[13];
  const float* bgo = (const float*)d_in[14];
  const float* Wlo = (const float*)d_in[15];
  const float* blo = (const float*)d_in[16];

  u16* ws   = (u16*)d_ws;
  u16* wt   = ws + WT_OFF;
  float* b2 = (float*)(ws + B2_OFF);
  u16* a_t  = ws + AT_OFF;
  u16* b_tt = ws + BT_OFF;
  u16* k_t  = ws + KT_OFF;
  float* out = (float*)d_out;

  conv_kernel<<<387, 256, 0, stream>>>(Wga, Wla, Wgb, Wlb, Wgo, Wlo,
                                       lnw, lnb, onw, onb,
                                       bga, bla, bgb, blb, bgo, blo, wt, b2);
  stageA_kernel<<<4096, 256, 0, stream>>>(z, wt, b2, a_t, b_tt);
  stageT_kernel<<<2048, 256, 0, stream>>>(a_t, b_tt, k_t);
  stageC_kernel<<<4096, 256, 0, stream>>>(k_t, z, wt, b2, out);
}

// Round 3
// 601.893 us; speedup vs baseline: 1.3732x; 1.3732x over previous
//
#include <hip/hip_runtime.h>

typedef unsigned short u16;
typedef __attribute__((ext_vector_type(8))) short bf16x8;
typedef __attribute__((ext_vector_type(4))) float f32x4;

#define L_ 512
#define D_ 128
#define LL_ (512*512)
#define LP_ 136   // LDS pitch for 128-wide rows (16B-aligned)
#define TP_ 72    // LDS pitch for 64-wide rows

// workspace (u16 elements): wt | bias2(f32) | a_t | b_tt | k_t
#define WT_OFF 0
#define B2_OFF 98304            // 768 f32 = 1536 u16
#define AT_OFF (B2_OFF + 1536)
#define BT_OFF (AT_OFF + 128*LL_)
#define KT_OFF (BT_OFF + 128*LL_)

union U16x8 { uint4 u4; bf16x8 v; u16 s[8]; };
union U16x4 { ushort4 v; u16 s[4]; };

__device__ __forceinline__ u16 f2bf(float f){
  union { float f; unsigned int i; } w; w.f = f;
  unsigned int r = w.i + 0x7FFFu + ((w.i >> 16) & 1u);  // RNE
  return (u16)(r >> 16);
}
__device__ __forceinline__ float sigm(float x){
  return 1.0f / (1.0f + __expf(-x));
}

// prep: wt[w][n][k] = W_w[k][n] * lnscale[k] (bf16), and
// bias2[w][n] = b_w[n] + sum_k lnbias[k] * W_w[k][n] (f32).
// blocks 0..383: wt elements; blocks 384..386: bias2 (768 outputs).
__global__ __launch_bounds__(256) void conv_kernel(
    const float* __restrict__ Wga, const float* __restrict__ Wla,
    const float* __restrict__ Wgb, const float* __restrict__ Wlb,
    const float* __restrict__ Wgo, const float* __restrict__ Wlo,
    const float* __restrict__ lnw, const float* __restrict__ lnb,
    const float* __restrict__ onw, const float* __restrict__ onb,
    const float* __restrict__ bga, const float* __restrict__ bla,
    const float* __restrict__ bgb, const float* __restrict__ blb,
    const float* __restrict__ bgo, const float* __restrict__ blo,
    u16* __restrict__ wt, float* __restrict__ bias2)
{
  if (blockIdx.x < 384){
    int idx = blockIdx.x*256 + threadIdx.x;            // 0..98303
    int w = idx >> 14, rem = idx & 16383, n = rem >> 7, k = rem & 127;
    const float* src;
    switch (w){
      case 0: src = Wga; break; case 1: src = Wla; break; case 2: src = Wgb; break;
      case 3: src = Wlb; break; case 4: src = Wgo; break; default: src = Wlo;
    }
    float sc = (w == 5) ? onw[k] : lnw[k];
    wt[idx] = f2bf(src[k*128 + n] * sc);
  } else {
    int j = (blockIdx.x - 384)*256 + threadIdx.x;      // 0..767
    int w = j >> 7, n = j & 127;
    const float* src; const float* bs;
    switch (w){
      case 0: src = Wga; bs = bga; break; case 1: src = Wla; bs = bla; break;
      case 2: src = Wgb; bs = bgb; break; case 3: src = Wlb; bs = blb; break;
      case 4: src = Wgo; bs = bgo; break; default: src = Wlo; bs = blo;
    }
    const float* lb = (w == 5) ? onb : lnb;
    float acc = bs[n];
    for (int k = 0; k < 128; ++k) acc += lb[k] * src[k*128 + n];
    bias2[j] = acc;
  }
}

// C[128x128] += A_lds[128xK=128 (pitch LP_)] * B  (wtm is [N=128][K=128] bf16)
__device__ __forceinline__ void gemm128(const u16* znlds, const u16* __restrict__ wtm,
                                        int wm, int wn, int quad, int l16, f32x4 acc[4][4])
{
  bf16x8 bf[4][4];
#pragma unroll
  for (int nt = 0; nt < 4; ++nt){
    int n = wn*64 + nt*16 + l16;
#pragma unroll
    for (int kc = 0; kc < 4; ++kc){
      U16x8 u; u.u4 = *(const uint4*)(wtm + n*128 + kc*32 + quad*8);
      bf[nt][kc] = u.v;
    }
  }
#pragma unroll
  for (int mt = 0; mt < 4; ++mt){
    int row = wm*64 + mt*16 + l16;
    bf16x8 af[4];
#pragma unroll
    for (int kc = 0; kc < 4; ++kc)
      af[kc] = *(const bf16x8*)(znlds + row*LP_ + kc*32 + quad*8);
#pragma unroll
    for (int nt = 0; nt < 4; ++nt)
#pragma unroll
      for (int kc = 0; kc < 4; ++kc)
        acc[mt][nt] = __builtin_amdgcn_mfma_f32_16x16x32_bf16(af[kc], bf[nt][kc], acc[mt][nt], 0, 0, 0);
  }
}

// 64-row variant: C[64x128] += A_lds[64x128 (pitch LP_)] * B
__device__ __forceinline__ void gemm64(const u16* alds, const u16* __restrict__ wtm,
                                       int wm, int wn, int quad, int l16, f32x4 acc[2][4])
{
  bf16x8 bf[4][4];
#pragma unroll
  for (int nt = 0; nt < 4; ++nt){
    int n = wn*64 + nt*16 + l16;
#pragma unroll
    for (int kc = 0; kc < 4; ++kc){
      U16x8 u; u.u4 = *(const uint4*)(wtm + n*128 + kc*32 + quad*8);
      bf[nt][kc] = u.v;
    }
  }
#pragma unroll
  for (int mt = 0; mt < 2; ++mt){
    int row = wm*32 + mt*16 + l16;
    bf16x8 af[4];
#pragma unroll
    for (int kc = 0; kc < 4; ++kc)
      af[kc] = *(const bf16x8*)(alds + row*LP_ + kc*32 + quad*8);
#pragma unroll
    for (int nt = 0; nt < 4; ++nt)
#pragma unroll
      for (int kc = 0; kc < 4; ++kc)
        acc[mt][nt] = __builtin_amdgcn_mfma_f32_16x16x32_bf16(af[kc], bf[nt][kc], acc[mt][nt], 0, 0, 0);
  }
}

// type0 blocks (bid<2048): row tiles (fixed i)   -> a_t[c][i][m]
// type1 blocks:            column tiles (fixed j) -> b_tt[c][j][m]
// LN affine folded into wt/bias2; zn and trh share one LDS buffer (35 KB).
// NOTE: no min-blocks launch bound — forcing 4 capped VGPRs at 64 and spilled
// the 128-reg accumulator tile to scratch (+1.6 GB HBM traffic, r2 post-mortem).
__global__ __launch_bounds__(256) void stageA_kernel(
    const float* __restrict__ z, const u16* __restrict__ wt,
    const float* __restrict__ bias2,
    u16* __restrict__ a_t, u16* __restrict__ b_tt)
{
  __shared__ __align__(16) u16 smem[128*LP_];   // zn during gemms, trh afterwards
  u16* zn = smem;
  u16* trh = smem;

  const int bid = blockIdx.x;
  const int type = bid >> 11;
  const int tile = bid & 2047;
  const int outer = tile >> 2;   // i (type0) or j (type1)
  const int seg = tile & 3;

  const int t = threadIdx.x;
  const int r = t >> 1, h = t & 1;
  const int lane = t & 63, wave = t >> 6;
  const int quad = lane >> 4, l16 = lane & 15;
  const int wm = wave & 1, wn = wave >> 1;

  { // ---- LayerNorm (f32, no affine) of 128 z-rows into zn LDS (bf16) ----
    int gpos = (type == 0) ? (outer*L_ + seg*128 + r) : ((seg*128 + r)*L_ + outer);
    const float* zrow = z + gpos*D_ + h*64;
    float raw[64];
    float sum = 0.f, sq = 0.f;
#pragma unroll
    for (int q = 0; q < 16; ++q){
      float4 v = *(const float4*)(zrow + q*4);
      raw[q*4+0] = v.x; raw[q*4+1] = v.y; raw[q*4+2] = v.z; raw[q*4+3] = v.w;
      sum += v.x + v.y + v.z + v.w;
      sq  += v.x*v.x + v.y*v.y + v.z*v.z + v.w*v.w;
    }
    sum += __shfl_xor(sum, 1, 64);
    sq  += __shfl_xor(sq , 1, 64);
    float mu = sum * (1.f/128.f);
    float rstd = rsqrtf(sq*(1.f/128.f) - mu*mu + 1e-5f);
#pragma unroll
    for (int q = 0; q < 8; ++q){
      U16x8 o;
#pragma unroll
      for (int e = 0; e < 8; ++e)
        o.s[e] = f2bf((raw[q*8+e] - mu)*rstd);
      *(uint4*)(zn + r*LP_ + h*64 + q*8) = o.u4;
    }
  }
  __syncthreads();

  const u16* wg   = wt + (type ? 2 : 0)*16384;
  const u16* wl   = wt + (type ? 3 : 1)*16384;
  const float* bgp = bias2 + (type ? 2 : 0)*128;
  const float* blp = bias2 + (type ? 3 : 1)*128;
  const f32x4 z4 = {0.f, 0.f, 0.f, 0.f};

  f32x4 accG[4][4], accL[4][4];
#pragma unroll
  for (int mt = 0; mt < 4; ++mt)
#pragma unroll
    for (int nt = 0; nt < 4; ++nt){ accG[mt][nt] = z4; accL[mt][nt] = z4; }

  gemm128(zn, wg, wm, wn, quad, l16, accG);
#pragma unroll
  for (int nt = 0; nt < 4; ++nt){
    float bb = bgp[wn*64 + nt*16 + l16];
#pragma unroll
    for (int mt = 0; mt < 4; ++mt)
#pragma unroll
      for (int e = 0; e < 4; ++e)
        accG[mt][nt][e] = sigm(accG[mt][nt][e] + bb);
  }
  gemm128(zn, wl, wm, wn, quad, l16, accL);
#pragma unroll
  for (int nt = 0; nt < 4; ++nt){
    float bb = blp[wn*64 + nt*16 + l16];
#pragma unroll
    for (int mt = 0; mt < 4; ++mt)
#pragma unroll
      for (int e = 0; e < 4; ++e)
        accG[mt][nt][e] *= (accL[mt][nt][e] + bb);   // gated product in accG
  }

  __syncthreads();   // zn dead; trh may now overwrite the same LDS

  // ---- transpose-store product channel-major (wave-row split, 2 passes) ----
  u16* dst = type ? b_tt : a_t;
  const int base = outer*L_ + seg*128;
#pragma unroll
  for (int pass = 0; pass < 2; ++pass){
    if (wm == pass){
#pragma unroll
      for (int nt = 0; nt < 4; ++nt){
        int gcol = wn*64 + nt*16 + l16;
#pragma unroll
        for (int mt = 0; mt < 4; ++mt){
          U16x4 pk;
#pragma unroll
          for (int e = 0; e < 4; ++e)
            pk.s[e] = f2bf(accG[mt][nt][e]);
          *(ushort4*)(trh + gcol*TP_ + mt*16 + quad*4) = pk.v;
        }
      }
    }
    __syncthreads();
#pragma unroll
    for (int q = 0; q < 4; ++q){
      uint4 v = *(const uint4*)(trh + r*TP_ + h*32 + q*8);
      *(uint4*)(dst + r*LL_ + base + pass*64 + h*32 + q*8) = v;
    }
    __syncthreads();
  }
}

// k_t[c][i][j] = sum_m a_t[c][i][m] * b_tt[c][j][m]
// single-buffer 32 KB, global_load_lds w16 + XOR swizzle, XCD-swizzled grid.
__global__ __launch_bounds__(256) void stageT_kernel(
    const u16* __restrict__ a_t, const u16* __restrict__ b_tt, u16* __restrict__ k_t)
{
  __shared__ __align__(16) u16 As[128*64];   // 16 KiB
  __shared__ __align__(16) u16 Bs[128*64];   // 16 KiB
  const int bid = blockIdx.x;                 // 2048 = 8 * 256
  const int lid = (bid & 7)*256 + (bid >> 3); // XCD k owns 16 whole channels (4 MB = L2)
  const int c = lid >> 4, it = (lid >> 2) & 3, jt = lid & 3;
  const u16* Ab = a_t + c*LL_ + it*128*L_;
  const u16* Bb = b_tt + c*LL_ + jt*128*L_;
  const int t = threadIdx.x;
  const int lane = t & 63, wave = t >> 6;
  const int quad = lane >> 4, l16 = lane & 15;
  const int wm = wave & 1, wn = wave >> 1;
  const int sr8 = lane >> 3, scl = lane & 7;
  const int cgx = scl ^ sr8;                  // pre-swizzled source chunk (row&7 == sr8)
  const int swz = (l16 & 7) << 3;             // read-side XOR in u16 units (row&7 == l16&7)

  f32x4 acc[4][4];
  const f32x4 z4 = {0.f,0.f,0.f,0.f};
#pragma unroll
  for (int mt = 0; mt < 4; ++mt)
#pragma unroll
    for (int nt = 0; nt < 4; ++nt) acc[mt][nt] = z4;

  for (int kt = 0; kt < 8; ++kt){
    const int k0 = kt*64;
    // stage: LDS[row][cl] = G[row][cl ^ (row&7)] (involution; read applies same XOR)
#pragma unroll
    for (int q = 0; q < 4; ++q){
      int row = q*32 + wave*8 + sr8;
      __builtin_amdgcn_global_load_lds(
          (const __attribute__((address_space(1))) void*)(Ab + row*L_ + k0 + cgx*8),
          (__attribute__((address_space(3))) void*)(&As[(q*32 + wave*8)*64]),
          16, 0, 0);
    }
#pragma unroll
    for (int q = 0; q < 4; ++q){
      int row = q*32 + wave*8 + sr8;
      __builtin_amdgcn_global_load_lds(
          (const __attribute__((address_space(1))) void*)(Bb + row*L_ + k0 + cgx*8),
          (__attribute__((address_space(3))) void*)(&Bs[(q*32 + wave*8)*64]),
          16, 0, 0);
    }
    __syncthreads();   // compiler drains vmcnt before barrier -> tile resident
    bf16x8 bfr[4][2];
#pragma unroll
    for (int nt = 0; nt < 4; ++nt){
      int brow = wn*64 + nt*16 + l16;
#pragma unroll
      for (int ks = 0; ks < 2; ++ks)
        bfr[nt][ks] = *(const bf16x8*)(Bs + brow*64 + (((ks*4 + quad)*8) ^ swz));
    }
#pragma unroll
    for (int mt = 0; mt < 4; ++mt){
      int arow = wm*64 + mt*16 + l16;
      bf16x8 af[2];
#pragma unroll
      for (int ks = 0; ks < 2; ++ks)
        af[ks] = *(const bf16x8*)(As + arow*64 + (((ks*4 + quad)*8) ^ swz));
#pragma unroll
      for (int nt = 0; nt < 4; ++nt)
#pragma unroll
        for (int ks = 0; ks < 2; ++ks)
          acc[mt][nt] = __builtin_amdgcn_mfma_f32_16x16x32_bf16(af[ks], bfr[nt][ks], acc[mt][nt], 0, 0, 0);
    }
    __syncthreads();   // all reads done before next tile overwrites
  }

#pragma unroll
  for (int mt = 0; mt < 4; ++mt)
#pragma unroll
    for (int nt = 0; nt < 4; ++nt){
      int gcol = wn*64 + nt*16 + l16;
#pragma unroll
      for (int e = 0; e < 4; ++e){
        int grow = wm*64 + mt*16 + quad*4 + e;
        k_t[c*LL_ + (it*128 + grow)*L_ + jt*128 + gcol] = f2bf(acc[mt][nt][e]);
      }
    }
}

// out[pos][d] = sigmoid(LN(z)[pos]@Wgo' + bgo') * (LN_c(k)[pos]@Wlo' + blo'), f32 out
// kl and znp alias one LDS buffer (36 KB total); LN affine folded.
__global__ __launch_bounds__(256) void stageC_kernel(
    const u16* __restrict__ k_t, const float* __restrict__ z,
    const u16* __restrict__ wt, const float* __restrict__ bias2,
    float* __restrict__ out)
{
  __shared__ __align__(16) u16 zn2[64*LP_];    // LN_c(k) [j][c]  (17 KB)
  __shared__ __align__(16) u16 kbuf[128*TP_];  // k tile, later LN(z) [pos][c] (18 KB)
  const u16* wtgo = wt + 4*16384;
  const u16* wtlo = wt + 5*16384;
  const float* bgo2 = bias2 + 4*128;
  const float* blo2 = bias2 + 5*128;
  const int bx = blockIdx.x;
  const int pos0 = (bx >> 3)*L_ + (bx & 7)*64;
  const int t = threadIdx.x, r = t >> 1, h = t & 1;
  const int rl4 = t >> 2, qd = t & 3;
  const int lane = t & 63, wave = t >> 6;
  const int quad = lane >> 4, l16 = lane & 15;
  const int wm = wave & 1, wn = wave >> 1;

  // phase 0: stage k tile [c][64 j]
#pragma unroll
  for (int q = 0; q < 4; ++q)
    *(uint4*)(kbuf + r*TP_ + h*32 + q*8) = *(const uint4*)(k_t + r*LL_ + pos0 + h*32 + q*8);
  __syncthreads();

  { // phase 1: zn2 = LN over channels of k for column j=rl4 (4 threads/column via qd)
    float sum = 0.f, sq = 0.f;
    float kv[32];
#pragma unroll
    for (int q = 0; q < 32; ++q){
      union { unsigned int i; float f; } w;
      w.i = ((unsigned int)kbuf[(qd*32 + q)*TP_ + rl4]) << 16;
      kv[q] = w.f; sum += w.f; sq += w.f*w.f;
    }
    sum += __shfl_xor(sum, 1, 64); sq += __shfl_xor(sq, 1, 64);
    sum += __shfl_xor(sum, 2, 64); sq += __shfl_xor(sq, 2, 64);
    float mu = sum*(1.f/128.f);
    float rstd = rsqrtf(sq*(1.f/128.f) - mu*mu + 1e-5f);
#pragma unroll
    for (int q = 0; q < 4; ++q){
      U16x8 o;
#pragma unroll
      for (int e = 0; e < 8; ++e)
        o.s[e] = f2bf((kv[q*8+e] - mu)*rstd);
      *(uint4*)(zn2 + rl4*LP_ + qd*32 + q*8) = o.u4;
    }
  }
  __syncthreads();   // kbuf (k tile) dead; reuse for LN(z)

  { // phase 2: kbuf = LN(z) row pos0+rl4 (4 threads/position via qd), f32 source
    const float* zr = z + (pos0 + rl4)*D_ + qd*32;
    float zv[32];
    float sum = 0.f, sq = 0.f;
#pragma unroll
    for (int q = 0; q < 8; ++q){
      float4 v = *(const float4*)(zr + q*4);
      zv[q*4+0] = v.x; zv[q*4+1] = v.y; zv[q*4+2] = v.z; zv[q*4+3] = v.w;
      sum += v.x + v.y + v.z + v.w;
      sq  += v.x*v.x + v.y*v.y + v.z*v.z + v.w*v.w;
    }
    sum += __shfl_xor(sum, 1, 64); sq += __shfl_xor(sq, 1, 64);
    sum += __shfl_xor(sum, 2, 64); sq += __shfl_xor(sq, 2, 64);
    float mu = sum*(1.f/128.f);
    float rstd = rsqrtf(sq*(1.f/128.f) - mu*mu + 1e-5f);
#pragma unroll
    for (int q = 0; q < 4; ++q){
      U16x8 o;
#pragma unroll
      for (int e = 0; e < 8; ++e)
        o.s[e] = f2bf((zv[q*8+e] - mu)*rstd);
      *(uint4*)(kbuf + rl4*LP_ + qd*32 + q*8) = o.u4;
    }
  }
  __syncthreads();

  f32x4 accK[2][4], accO[2][4];
  const f32x4 z4 = {0.f,0.f,0.f,0.f};
#pragma unroll
  for (int mt = 0; mt < 2; ++mt)
#pragma unroll
    for (int nt = 0; nt < 4; ++nt){ accK[mt][nt] = z4; accO[mt][nt] = z4; }

  gemm64(zn2,  wtlo, wm, wn, quad, l16, accK);
  gemm64(kbuf, wtgo, wm, wn, quad, l16, accO);

#pragma unroll
  for (int nt = 0; nt < 4; ++nt){
    int gcol = wn*64 + nt*16 + l16;
    float bo = bgo2[gcol], bl = blo2[gcol];
#pragma unroll
    for (int mt = 0; mt < 2; ++mt)
#pragma unroll
      for (int e = 0; e < 4; ++e){
        int grow = wm*32 + mt*16 + quad*4 + e;
        float s = sigm(accO[mt][nt][e] + bo);
        out[(pos0 + grow)*D_ + gcol] = s*(accK[mt][nt][e] + bl);
      }
  }
}

extern "C" void kernel_launch(void* const* d_in, const int* in_sizes, int n_in,
                              void* d_out, int out_size, void* d_ws, size_t ws_size,
                              hipStream_t stream)
{
  const float* z   = (const float*)d_in[0];
  const float* lnw = (const float*)d_in[1];
  const float* lnb = (const float*)d_in[2];
  const float* Wga = (const float*)d_in[3];
  const float* bga = (const float*)d_in[4];
  const float* Wla = (const float*)d_in[5];
  const float* bla = (const float*)d_in[6];
  const float* Wgb = (const float*)d_in[7];
  const float* bgb = (const float*)d_in[8];
  const float* Wlb = (const float*)d_in[9];
  const float* blb = (const float*)d_in[10];
  const float* onw = (const float*)d_in[11];
  const float* onb = (const float*)d_in[12];
  const float* Wgo = (const float*)d_in[13];
  const float* bgo = (const float*)d_in[14];
  const float* Wlo = (const float*)d_in[15];
  const float* blo = (const float*)d_in[16];

  u16* ws   = (u16*)d_ws;
  u16* wt   = ws + WT_OFF;
  float* b2 = (float*)(ws + B2_OFF);
  u16* a_t  = ws + AT_OFF;
  u16* b_tt = ws + BT_OFF;
  u16* k_t  = ws + KT_OFF;
  float* out = (float*)d_out;

  conv_kernel<<<387, 256, 0, stream>>>(Wga, Wla, Wgb, Wlb, Wgo, Wlo,
                                       lnw, lnb, onw, onb,
                                       bga, bla, bgb, blb, bgo, blo, wt, b2);
  stageA_kernel<<<4096, 256, 0, stream>>>(z, wt, b2, a_t, b_tt);
  stageT_kernel<<<2048, 256, 0, stream>>>(a_t, b_tt, k_t);
  stageC_kernel<<<4096, 256, 0, stream>>>(k_t, z, wt, b2, out);
}

// Round 4
// 576.159 us; speedup vs baseline: 1.4345x; 1.0447x over previous
//
#include <hip/hip_runtime.h>

typedef unsigned short u16;
typedef __attribute__((ext_vector_type(8))) short bf16x8;
typedef __attribute__((ext_vector_type(4))) float f32x4;

#define L_ 512
#define D_ 128
#define LL_ (512*512)
#define LP_ 136   // LDS pitch for 128-wide rows (16B-aligned)
#define TP_ 72    // LDS pitch for 64-wide rows

// ---- workspace layouts (u16 elements) ----
// v2 (with precomputed zn): wt | bias2 | zn | a_t | b_tt | k_t  = 268.6 MB
#define WT_OFF 0
#define B2_OFF 98304            // 768 f32 = 1536 u16
#define ZN_OFF (B2_OFF + 1536)
#define AT2_OFF (ZN_OFF + 128*LL_)
#define BT2_OFF (AT2_OFF + 128*LL_)
#define KT2_OFF (BT2_OFF + 128*LL_)
#define WS2_NEED_BYTES ((size_t)(KT2_OFF + 128*LL_) * 2)
// v1 fallback (round-3 layout): wt | bias2 | a_t | b_tt | k_t = 192 MB
#define AT1_OFF (B2_OFF + 1536)
#define BT1_OFF (AT1_OFF + 128*LL_)
#define KT1_OFF (BT1_OFF + 128*LL_)

union U16x8 { uint4 u4; bf16x8 v; u16 s[8]; };
union U16x4 { ushort4 v; u16 s[4]; };

__device__ __forceinline__ u16 f2bf(float f){
  union { float f; unsigned int i; } w; w.f = f;
  unsigned int r = w.i + 0x7FFFu + ((w.i >> 16) & 1u);  // RNE
  return (u16)(r >> 16);
}
__device__ __forceinline__ float sigm(float x){
  return 1.0f / (1.0f + __expf(-x));
}

// prep: wt[w][n][k] = W_w[k][n] * lnscale[k] (bf16), and
// bias2[w][n] = b_w[n] + sum_k lnbias[k] * W_w[k][n] (f32).
__global__ __launch_bounds__(256) void conv_kernel(
    const float* __restrict__ Wga, const float* __restrict__ Wla,
    const float* __restrict__ Wgb, const float* __restrict__ Wlb,
    const float* __restrict__ Wgo, const float* __restrict__ Wlo,
    const float* __restrict__ lnw, const float* __restrict__ lnb,
    const float* __restrict__ onw, const float* __restrict__ onb,
    const float* __restrict__ bga, const float* __restrict__ bla,
    const float* __restrict__ bgb, const float* __restrict__ blb,
    const float* __restrict__ bgo, const float* __restrict__ blo,
    u16* __restrict__ wt, float* __restrict__ bias2)
{
  if (blockIdx.x < 384){
    int idx = blockIdx.x*256 + threadIdx.x;            // 0..98303
    int w = idx >> 14, rem = idx & 16383, n = rem >> 7, k = rem & 127;
    const float* src;
    switch (w){
      case 0: src = Wga; break; case 1: src = Wla; break; case 2: src = Wgb; break;
      case 3: src = Wlb; break; case 4: src = Wgo; break; default: src = Wlo;
    }
    float sc = (w == 5) ? onw[k] : lnw[k];
    wt[idx] = f2bf(src[k*128 + n] * sc);
  } else {
    int j = (blockIdx.x - 384)*256 + threadIdx.x;      // 0..767
    int w = j >> 7, n = j & 127;
    const float* src; const float* bs;
    switch (w){
      case 0: src = Wga; bs = bga; break; case 1: src = Wla; bs = bla; break;
      case 2: src = Wgb; bs = bgb; break; case 3: src = Wlb; bs = blb; break;
      case 4: src = Wgo; bs = bgo; break; default: src = Wlo; bs = blo;
    }
    const float* lb = (w == 5) ? onb : lnb;
    float acc = bs[n];
    for (int k = 0; k < 128; ++k) acc += lb[k] * src[k*128 + n];
    bias2[j] = acc;
  }
}

// stageZ: zn[pos][c] = (z[pos][c] - mu) * rstd   (bf16), computed ONCE.
__global__ __launch_bounds__(256) void stageZ_kernel(
    const float* __restrict__ z, u16* __restrict__ zn_g)
{
  const int t = threadIdx.x, r = t >> 1, h = t & 1;
  const int row = blockIdx.x*128 + r;
  const float* zrow = z + (long)row*D_ + h*64;
  float raw[64];
  float sum = 0.f, sq = 0.f;
#pragma unroll
  for (int q = 0; q < 16; ++q){
    float4 v = *(const float4*)(zrow + q*4);
    raw[q*4+0] = v.x; raw[q*4+1] = v.y; raw[q*4+2] = v.z; raw[q*4+3] = v.w;
    sum += v.x + v.y + v.z + v.w;
    sq  += v.x*v.x + v.y*v.y + v.z*v.z + v.w*v.w;
  }
  sum += __shfl_xor(sum, 1, 64);
  sq  += __shfl_xor(sq , 1, 64);
  float mu = sum * (1.f/128.f);
  float rstd = rsqrtf(sq*(1.f/128.f) - mu*mu + 1e-5f);
  u16* orow = zn_g + (long)row*D_ + h*64;
#pragma unroll
  for (int q = 0; q < 8; ++q){
    U16x8 o;
#pragma unroll
    for (int e = 0; e < 8; ++e)
      o.s[e] = f2bf(raw[q*8+e] - mu > 0 ? (raw[q*8+e] - mu)*rstd : (raw[q*8+e] - mu)*rstd);
    *(uint4*)(orow + q*8) = o.u4;
  }
}

// gemm over pitched LDS (LP_), used by fallback stageA/stageC and v2 stageC.
__device__ __forceinline__ void gemm128(const u16* znlds, const u16* __restrict__ wtm,
                                        int wm, int wn, int quad, int l16, f32x4 acc[4][4])
{
  bf16x8 bf[4][4];
#pragma unroll
  for (int nt = 0; nt < 4; ++nt){
    int n = wn*64 + nt*16 + l16;
#pragma unroll
    for (int kc = 0; kc < 4; ++kc){
      U16x8 u; u.u4 = *(const uint4*)(wtm + n*128 + kc*32 + quad*8);
      bf[nt][kc] = u.v;
    }
  }
#pragma unroll
  for (int mt = 0; mt < 4; ++mt){
    int row = wm*64 + mt*16 + l16;
    bf16x8 af[4];
#pragma unroll
    for (int kc = 0; kc < 4; ++kc)
      af[kc] = *(const bf16x8*)(znlds + row*LP_ + kc*32 + quad*8);
#pragma unroll
    for (int nt = 0; nt < 4; ++nt)
#pragma unroll
      for (int kc = 0; kc < 4; ++kc)
        acc[mt][nt] = __builtin_amdgcn_mfma_f32_16x16x32_bf16(af[kc], bf[nt][kc], acc[mt][nt], 0, 0, 0);
  }
}

// gemm over XOR-swizzled linear LDS (pitch 128, chunk^=(row&7)) — v2 stageA.
__device__ __forceinline__ void gemm128s(const u16* znS, const u16* __restrict__ wtm,
                                         int wm, int wn, int quad, int l16, f32x4 acc[4][4])
{
  bf16x8 bf[4][4];
#pragma unroll
  for (int nt = 0; nt < 4; ++nt){
    int n = wn*64 + nt*16 + l16;
#pragma unroll
    for (int kc = 0; kc < 4; ++kc){
      U16x8 u; u.u4 = *(const uint4*)(wtm + n*128 + kc*32 + quad*8);
      bf[nt][kc] = u.v;
    }
  }
  const int r7 = l16 & 7;
#pragma unroll
  for (int mt = 0; mt < 4; ++mt){
    int row = wm*64 + mt*16 + l16;
    bf16x8 af[4];
#pragma unroll
    for (int kc = 0; kc < 4; ++kc)
      af[kc] = *(const bf16x8*)(znS + row*128 + (((kc*4 + quad) ^ r7) << 3));
#pragma unroll
    for (int nt = 0; nt < 4; ++nt)
#pragma unroll
      for (int kc = 0; kc < 4; ++kc)
        acc[mt][nt] = __builtin_amdgcn_mfma_f32_16x16x32_bf16(af[kc], bf[nt][kc], acc[mt][nt], 0, 0, 0);
  }
}

__device__ __forceinline__ void gemm64(const u16* alds, const u16* __restrict__ wtm,
                                       int wm, int wn, int quad, int l16, f32x4 acc[2][4])
{
  bf16x8 bf[4][4];
#pragma unroll
  for (int nt = 0; nt < 4; ++nt){
    int n = wn*64 + nt*16 + l16;
#pragma unroll
    for (int kc = 0; kc < 4; ++kc){
      U16x8 u; u.u4 = *(const uint4*)(wtm + n*128 + kc*32 + quad*8);
      bf[nt][kc] = u.v;
    }
  }
#pragma unroll
  for (int mt = 0; mt < 2; ++mt){
    int row = wm*32 + mt*16 + l16;
    bf16x8 af[4];
#pragma unroll
    for (int kc = 0; kc < 4; ++kc)
      af[kc] = *(const bf16x8*)(alds + row*LP_ + kc*32 + quad*8);
#pragma unroll
    for (int nt = 0; nt < 4; ++nt)
#pragma unroll
      for (int kc = 0; kc < 4; ++kc)
        acc[mt][nt] = __builtin_amdgcn_mfma_f32_16x16x32_bf16(af[kc], bf[nt][kc], acc[mt][nt], 0, 0, 0);
  }
}

// ---------- v2 stageA: zn precomputed; stage tile via global_load_lds + XOR swizzle ----------
__global__ __launch_bounds__(256) void stageA2_kernel(
    const u16* __restrict__ zn_g, const u16* __restrict__ wt,
    const float* __restrict__ bias2,
    u16* __restrict__ a_t, u16* __restrict__ b_tt)
{
  __shared__ __align__(16) u16 znS[128*128];   // 32 KiB; reused as trh after gemms

  const int bid = blockIdx.x;
  const int type = bid >> 11;
  const int tile = bid & 2047;
  const int outer = tile >> 2;   // i (type0) or j (type1)
  const int seg = tile & 3;

  const int t = threadIdx.x;
  const int r = t >> 1, h = t & 1;
  const int lane = t & 63, wave = t >> 6;
  const int quad = lane >> 4, l16 = lane & 15;
  const int wm = wave & 1, wn = wave >> 1;

  // ---- stage zn tile: LDS[row][cl] = zn_g[pos(row)][cl ^ (row&7)] (16B chunks) ----
  {
    const int lr = lane >> 4, lc = lane & 15;
    const int r7s = (wave*4 + lr) & 7;
    const int cgx = lc ^ r7s;
#pragma unroll
    for (int q = 0; q < 8; ++q){
      int row = q*16 + wave*4 + lr;
      int gpos = (type == 0) ? (outer*L_ + seg*128 + row) : ((seg*128 + row)*L_ + outer);
      __builtin_amdgcn_global_load_lds(
          (const __attribute__((address_space(1))) void*)(zn_g + (long)gpos*D_ + cgx*8),
          (__attribute__((address_space(3))) void*)(&znS[(q*16 + wave*4)*128]),
          16, 0, 0);
    }
  }
  __syncthreads();

  const u16* wg   = wt + (type ? 2 : 0)*16384;
  const u16* wl   = wt + (type ? 3 : 1)*16384;
  const float* bgp = bias2 + (type ? 2 : 0)*128;
  const float* blp = bias2 + (type ? 3 : 1)*128;
  const f32x4 z4 = {0.f, 0.f, 0.f, 0.f};

  f32x4 accG[4][4], accL[4][4];
#pragma unroll
  for (int mt = 0; mt < 4; ++mt)
#pragma unroll
    for (int nt = 0; nt < 4; ++nt){ accG[mt][nt] = z4; accL[mt][nt] = z4; }

  gemm128s(znS, wg, wm, wn, quad, l16, accG);
#pragma unroll
  for (int nt = 0; nt < 4; ++nt){
    float bb = bgp[wn*64 + nt*16 + l16];
#pragma unroll
    for (int mt = 0; mt < 4; ++mt)
#pragma unroll
      for (int e = 0; e < 4; ++e)
        accG[mt][nt][e] = sigm(accG[mt][nt][e] + bb);
  }
  gemm128s(znS, wl, wm, wn, quad, l16, accL);
#pragma unroll
  for (int nt = 0; nt < 4; ++nt){
    float bb = blp[wn*64 + nt*16 + l16];
#pragma unroll
    for (int mt = 0; mt < 4; ++mt)
#pragma unroll
      for (int e = 0; e < 4; ++e)
        accG[mt][nt][e] *= (accL[mt][nt][e] + bb);   // gated product in accG
  }

  __syncthreads();   // znS dead; reuse as trh

  u16* trh = znS;
  u16* dst = type ? b_tt : a_t;
  const int base = outer*L_ + seg*128;
#pragma unroll
  for (int pass = 0; pass < 2; ++pass){
    if (wm == pass){
#pragma unroll
      for (int nt = 0; nt < 4; ++nt){
        int gcol = wn*64 + nt*16 + l16;
#pragma unroll
        for (int mt = 0; mt < 4; ++mt){
          U16x4 pk;
#pragma unroll
          for (int e = 0; e < 4; ++e)
            pk.s[e] = f2bf(accG[mt][nt][e]);
          *(ushort4*)(trh + gcol*TP_ + mt*16 + quad*4) = pk.v;
        }
      }
    }
    __syncthreads();
#pragma unroll
    for (int q = 0; q < 4; ++q){
      uint4 v = *(const uint4*)(trh + r*TP_ + h*32 + q*8);
      *(uint4*)(dst + r*LL_ + base + pass*64 + h*32 + q*8) = v;
    }
    __syncthreads();
  }
}

// ---------- v1 stageA (round-3 fallback, LN inline) ----------
__global__ __launch_bounds__(256) void stageA_kernel(
    const float* __restrict__ z, const u16* __restrict__ wt,
    const float* __restrict__ bias2,
    u16* __restrict__ a_t, u16* __restrict__ b_tt)
{
  __shared__ __align__(16) u16 smem[128*LP_];
  u16* zn = smem;
  u16* trh = smem;

  const int bid = blockIdx.x;
  const int type = bid >> 11;
  const int tile = bid & 2047;
  const int outer = tile >> 2;
  const int seg = tile & 3;

  const int t = threadIdx.x;
  const int r = t >> 1, h = t & 1;
  const int lane = t & 63, wave = t >> 6;
  const int quad = lane >> 4, l16 = lane & 15;
  const int wm = wave & 1, wn = wave >> 1;

  {
    int gpos = (type == 0) ? (outer*L_ + seg*128 + r) : ((seg*128 + r)*L_ + outer);
    const float* zrow = z + gpos*D_ + h*64;
    float raw[64];
    float sum = 0.f, sq = 0.f;
#pragma unroll
    for (int q = 0; q < 16; ++q){
      float4 v = *(const float4*)(zrow + q*4);
      raw[q*4+0] = v.x; raw[q*4+1] = v.y; raw[q*4+2] = v.z; raw[q*4+3] = v.w;
      sum += v.x + v.y + v.z + v.w;
      sq  += v.x*v.x + v.y*v.y + v.z*v.z + v.w*v.w;
    }
    sum += __shfl_xor(sum, 1, 64);
    sq  += __shfl_xor(sq , 1, 64);
    float mu = sum * (1.f/128.f);
    float rstd = rsqrtf(sq*(1.f/128.f) - mu*mu + 1e-5f);
#pragma unroll
    for (int q = 0; q < 8; ++q){
      U16x8 o;
#pragma unroll
      for (int e = 0; e < 8; ++e)
        o.s[e] = f2bf((raw[q*8+e] - mu)*rstd);
      *(uint4*)(zn + r*LP_ + h*64 + q*8) = o.u4;
    }
  }
  __syncthreads();

  const u16* wg   = wt + (type ? 2 : 0)*16384;
  const u16* wl   = wt + (type ? 3 : 1)*16384;
  const float* bgp = bias2 + (type ? 2 : 0)*128;
  const float* blp = bias2 + (type ? 3 : 1)*128;
  const f32x4 z4 = {0.f, 0.f, 0.f, 0.f};

  f32x4 accG[4][4], accL[4][4];
#pragma unroll
  for (int mt = 0; mt < 4; ++mt)
#pragma unroll
    for (int nt = 0; nt < 4; ++nt){ accG[mt][nt] = z4; accL[mt][nt] = z4; }

  gemm128(zn, wg, wm, wn, quad, l16, accG);
#pragma unroll
  for (int nt = 0; nt < 4; ++nt){
    float bb = bgp[wn*64 + nt*16 + l16];
#pragma unroll
    for (int mt = 0; mt < 4; ++mt)
#pragma unroll
      for (int e = 0; e < 4; ++e)
        accG[mt][nt][e] = sigm(accG[mt][nt][e] + bb);
  }
  gemm128(zn, wl, wm, wn, quad, l16, accL);
#pragma unroll
  for (int nt = 0; nt < 4; ++nt){
    float bb = blp[wn*64 + nt*16 + l16];
#pragma unroll
    for (int mt = 0; mt < 4; ++mt)
#pragma unroll
      for (int e = 0; e < 4; ++e)
        accG[mt][nt][e] *= (accL[mt][nt][e] + bb);
  }

  __syncthreads();

  u16* dst = type ? b_tt : a_t;
  const int base = outer*L_ + seg*128;
#pragma unroll
  for (int pass = 0; pass < 2; ++pass){
    if (wm == pass){
#pragma unroll
      for (int nt = 0; nt < 4; ++nt){
        int gcol = wn*64 + nt*16 + l16;
#pragma unroll
        for (int mt = 0; mt < 4; ++mt){
          U16x4 pk;
#pragma unroll
          for (int e = 0; e < 4; ++e)
            pk.s[e] = f2bf(accG[mt][nt][e]);
          *(ushort4*)(trh + gcol*TP_ + mt*16 + quad*4) = pk.v;
        }
      }
    }
    __syncthreads();
#pragma unroll
    for (int q = 0; q < 4; ++q){
      uint4 v = *(const uint4*)(trh + r*TP_ + h*32 + q*8);
      *(uint4*)(dst + r*LL_ + base + pass*64 + h*32 + q*8) = v;
    }
    __syncthreads();
  }
}

// k_t[c][i][j] = sum_m a_t[c][i][m] * b_tt[c][j][m]
__global__ __launch_bounds__(256) void stageT_kernel(
    const u16* __restrict__ a_t, const u16* __restrict__ b_tt, u16* __restrict__ k_t)
{
  __shared__ __align__(16) u16 As[128*64];
  __shared__ __align__(16) u16 Bs[128*64];
  const int bid = blockIdx.x;                 // 2048 = 8 * 256
  const int lid = (bid & 7)*256 + (bid >> 3); // XCD k owns 16 whole channels
  const int c = lid >> 4, it = (lid >> 2) & 3, jt = lid & 3;
  const u16* Ab = a_t + c*LL_ + it*128*L_;
  const u16* Bb = b_tt + c*LL_ + jt*128*L_;
  const int t = threadIdx.x;
  const int lane = t & 63, wave = t >> 6;
  const int quad = lane >> 4, l16 = lane & 15;
  const int wm = wave & 1, wn = wave >> 1;
  const int sr8 = lane >> 3, scl = lane & 7;
  const int cgx = scl ^ sr8;
  const int swz = (l16 & 7) << 3;

  f32x4 acc[4][4];
  const f32x4 z4 = {0.f,0.f,0.f,0.f};
#pragma unroll
  for (int mt = 0; mt < 4; ++mt)
#pragma unroll
    for (int nt = 0; nt < 4; ++nt) acc[mt][nt] = z4;

  for (int kt = 0; kt < 8; ++kt){
    const int k0 = kt*64;
#pragma unroll
    for (int q = 0; q < 4; ++q){
      int row = q*32 + wave*8 + sr8;
      __builtin_amdgcn_global_load_lds(
          (const __attribute__((address_space(1))) void*)(Ab + row*L_ + k0 + cgx*8),
          (__attribute__((address_space(3))) void*)(&As[(q*32 + wave*8)*64]),
          16, 0, 0);
    }
#pragma unroll
    for (int q = 0; q < 4; ++q){
      int row = q*32 + wave*8 + sr8;
      __builtin_amdgcn_global_load_lds(
          (const __attribute__((address_space(1))) void*)(Bb + row*L_ + k0 + cgx*8),
          (__attribute__((address_space(3))) void*)(&Bs[(q*32 + wave*8)*64]),
          16, 0, 0);
    }
    __syncthreads();
    bf16x8 bfr[4][2];
#pragma unroll
    for (int nt = 0; nt < 4; ++nt){
      int brow = wn*64 + nt*16 + l16;
#pragma unroll
      for (int ks = 0; ks < 2; ++ks)
        bfr[nt][ks] = *(const bf16x8*)(Bs + brow*64 + (((ks*4 + quad)*8) ^ swz));
    }
#pragma unroll
    for (int mt = 0; mt < 4; ++mt){
      int arow = wm*64 + mt*16 + l16;
      bf16x8 af[2];
#pragma unroll
      for (int ks = 0; ks < 2; ++ks)
        af[ks] = *(const bf16x8*)(As + arow*64 + (((ks*4 + quad)*8) ^ swz));
#pragma unroll
      for (int nt = 0; nt < 4; ++nt)
#pragma unroll
        for (int ks = 0; ks < 2; ++ks)
          acc[mt][nt] = __builtin_amdgcn_mfma_f32_16x16x32_bf16(af[ks], bfr[nt][ks], acc[mt][nt], 0, 0, 0);
    }
    __syncthreads();
  }

#pragma unroll
  for (int mt = 0; mt < 4; ++mt)
#pragma unroll
    for (int nt = 0; nt < 4; ++nt){
      int gcol = wn*64 + nt*16 + l16;
#pragma unroll
      for (int e = 0; e < 4; ++e){
        int grow = wm*64 + mt*16 + quad*4 + e;
        k_t[c*LL_ + (it*128 + grow)*L_ + jt*128 + gcol] = f2bf(acc[mt][nt][e]);
      }
    }
}

// ---------- v2 stageC: zn precomputed (phase-2 LN replaced by vector copy) ----------
__global__ __launch_bounds__(256) void stageC2_kernel(
    const u16* __restrict__ k_t, const u16* __restrict__ zn_g,
    const u16* __restrict__ wt, const float* __restrict__ bias2,
    float* __restrict__ out)
{
  __shared__ __align__(16) u16 zn2[64*LP_];
  __shared__ __align__(16) u16 kbuf[128*TP_];
  const u16* wtgo = wt + 4*16384;
  const u16* wtlo = wt + 5*16384;
  const float* bgo2 = bias2 + 4*128;
  const float* blo2 = bias2 + 5*128;
  const int bx = blockIdx.x;
  const int pos0 = (bx >> 3)*L_ + (bx & 7)*64;
  const int t = threadIdx.x, r = t >> 1, h = t & 1;
  const int rl4 = t >> 2, qd = t & 3;
  const int lane = t & 63, wave = t >> 6;
  const int quad = lane >> 4, l16 = lane & 15;
  const int wm = wave & 1, wn = wave >> 1;

#pragma unroll
  for (int q = 0; q < 4; ++q)
    *(uint4*)(kbuf + r*TP_ + h*32 + q*8) = *(const uint4*)(k_t + r*LL_ + pos0 + h*32 + q*8);
  __syncthreads();

  { // LN over channels of k for column j=rl4
    float sum = 0.f, sq = 0.f;
    float kv[32];
#pragma unroll
    for (int q = 0; q < 32; ++q){
      union { unsigned int i; float f; } w;
      w.i = ((unsigned int)kbuf[(qd*32 + q)*TP_ + rl4]) << 16;
      kv[q] = w.f; sum += w.f; sq += w.f*w.f;
    }
    sum += __shfl_xor(sum, 1, 64); sq += __shfl_xor(sq, 1, 64);
    sum += __shfl_xor(sum, 2, 64); sq += __shfl_xor(sq, 2, 64);
    float mu = sum*(1.f/128.f);
    float rstd = rsqrtf(sq*(1.f/128.f) - mu*mu + 1e-5f);
#pragma unroll
    for (int q = 0; q < 4; ++q){
      U16x8 o;
#pragma unroll
      for (int e = 0; e < 8; ++e)
        o.s[e] = f2bf((kv[q*8+e] - mu)*rstd);
      *(uint4*)(zn2 + rl4*LP_ + qd*32 + q*8) = o.u4;
    }
  }
  __syncthreads();   // kbuf (k tile) dead; reuse for zn rows

  { // copy zn rows [pos][c]
    const u16* zr = zn_g + (long)(pos0 + rl4)*D_ + qd*32;
    *(uint4*)(kbuf + rl4*LP_ + qd*32     ) = *(const uint4*)(zr);
    *(uint4*)(kbuf + rl4*LP_ + qd*32 + 8 ) = *(const uint4*)(zr + 8);
    *(uint4*)(kbuf + rl4*LP_ + qd*32 + 16) = *(const uint4*)(zr + 16);
    *(uint4*)(kbuf + rl4*LP_ + qd*32 + 24) = *(const uint4*)(zr + 24);
  }
  __syncthreads();

  f32x4 accK[2][4], accO[2][4];
  const f32x4 z4 = {0.f,0.f,0.f,0.f};
#pragma unroll
  for (int mt = 0; mt < 2; ++mt)
#pragma unroll
    for (int nt = 0; nt < 4; ++nt){ accK[mt][nt] = z4; accO[mt][nt] = z4; }

  gemm64(zn2,  wtlo, wm, wn, quad, l16, accK);
  gemm64(kbuf, wtgo, wm, wn, quad, l16, accO);

#pragma unroll
  for (int nt = 0; nt < 4; ++nt){
    int gcol = wn*64 + nt*16 + l16;
    float bo = bgo2[gcol], bl = blo2[gcol];
#pragma unroll
    for (int mt = 0; mt < 2; ++mt)
#pragma unroll
      for (int e = 0; e < 4; ++e){
        int grow = wm*32 + mt*16 + quad*4 + e;
        float s = sigm(accO[mt][nt][e] + bo);
        out[(pos0 + grow)*D_ + gcol] = s*(accK[mt][nt][e] + bl);
      }
  }
}

// ---------- v1 stageC (round-3 fallback, LN(z) inline) ----------
__global__ __launch_bounds__(256) void stageC_kernel(
    const u16* __restrict__ k_t, const float* __restrict__ z,
    const u16* __restrict__ wt, const float* __restrict__ bias2,
    float* __restrict__ out)
{
  __shared__ __align__(16) u16 zn2[64*LP_];
  __shared__ __align__(16) u16 kbuf[128*TP_];
  const u16* wtgo = wt + 4*16384;
  const u16* wtlo = wt + 5*16384;
  const float* bgo2 = bias2 + 4*128;
  const float* blo2 = bias2 + 5*128;
  const int bx = blockIdx.x;
  const int pos0 = (bx >> 3)*L_ + (bx & 7)*64;
  const int t = threadIdx.x, r = t >> 1, h = t & 1;
  const int rl4 = t >> 2, qd = t & 3;
  const int lane = t & 63, wave = t >> 6;
  const int quad = lane >> 4, l16 = lane & 15;
  const int wm = wave & 1, wn = wave >> 1;

#pragma unroll
  for (int q = 0; q < 4; ++q)
    *(uint4*)(kbuf + r*TP_ + h*32 + q*8) = *(const uint4*)(k_t + r*LL_ + pos0 + h*32 + q*8);
  __syncthreads();

  {
    float sum = 0.f, sq = 0.f;
    float kv[32];
#pragma unroll
    for (int q = 0; q < 32; ++q){
      union { unsigned int i; float f; } w;
      w.i = ((unsigned int)kbuf[(qd*32 + q)*TP_ + rl4]) << 16;
      kv[q] = w.f; sum += w.f; sq += w.f*w.f;
    }
    sum += __shfl_xor(sum, 1, 64); sq += __shfl_xor(sq, 1, 64);
    sum += __shfl_xor(sum, 2, 64); sq += __shfl_xor(sq, 2, 64);
    float mu = sum*(1.f/128.f);
    float rstd = rsqrtf(sq*(1.f/128.f) - mu*mu + 1e-5f);
#pragma unroll
    for (int q = 0; q < 4; ++q){
      U16x8 o;
#pragma unroll
      for (int e = 0; e < 8; ++e)
        o.s[e] = f2bf((kv[q*8+e] - mu)*rstd);
      *(uint4*)(zn2 + rl4*LP_ + qd*32 + q*8) = o.u4;
    }
  }
  __syncthreads();

  {
    const float* zr = z + (pos0 + rl4)*D_ + qd*32;
    float zv[32];
    float sum = 0.f, sq = 0.f;
#pragma unroll
    for (int q = 0; q < 8; ++q){
      float4 v = *(const float4*)(zr + q*4);
      zv[q*4+0] = v.x; zv[q*4+1] = v.y; zv[q*4+2] = v.z; zv[q*4+3] = v.w;
      sum += v.x + v.y + v.z + v.w;
      sq  += v.x*v.x + v.y*v.y + v.z*v.z + v.w*v.w;
    }
    sum += __shfl_xor(sum, 1, 64); sq += __shfl_xor(sq, 1, 64);
    sum += __shfl_xor(sum, 2, 64); sq += __shfl_xor(sq, 2, 64);
    float mu = sum*(1.f/128.f);
    float rstd = rsqrtf(sq*(1.f/128.f) - mu*mu + 1e-5f);
#pragma unroll
    for (int q = 0; q < 4; ++q){
      U16x8 o;
#pragma unroll
      for (int e = 0; e < 8; ++e)
        o.s[e] = f2bf((zv[q*8+e] - mu)*rstd);
      *(uint4*)(kbuf + rl4*LP_ + qd*32 + q*8) = o.u4;
    }
  }
  __syncthreads();

  f32x4 accK[2][4], accO[2][4];
  const f32x4 z4 = {0.f,0.f,0.f,0.f};
#pragma unroll
  for (int mt = 0; mt < 2; ++mt)
#pragma unroll
    for (int nt = 0; nt < 4; ++nt){ accK[mt][nt] = z4; accO[mt][nt] = z4; }

  gemm64(zn2,  wtlo, wm, wn, quad, l16, accK);
  gemm64(kbuf, wtgo, wm, wn, quad, l16, accO);

#pragma unroll
  for (int nt = 0; nt < 4; ++nt){
    int gcol = wn*64 + nt*16 + l16;
    float bo = bgo2[gcol], bl = blo2[gcol];
#pragma unroll
    for (int mt = 0; mt < 2; ++mt)
#pragma unroll
      for (int e = 0; e < 4; ++e){
        int grow = wm*32 + mt*16 + quad*4 + e;
        float s = sigm(accO[mt][nt][e] + bo);
        out[(pos0 + grow)*D_ + gcol] = s*(accK[mt][nt][e] + bl);
      }
  }
}

extern "C" void kernel_launch(void* const* d_in, const int* in_sizes, int n_in,
                              void* d_out, int out_size, void* d_ws, size_t ws_size,
                              hipStream_t stream)
{
  const float* z   = (const float*)d_in[0];
  const float* lnw = (const float*)d_in[1];
  const float* lnb = (const float*)d_in[2];
  const float* Wga = (const float*)d_in[3];
  const float* bga = (const float*)d_in[4];
  const float* Wla = (const float*)d_in[5];
  const float* bla = (const float*)d_in[6];
  const float* Wgb = (const float*)d_in[7];
  const float* bgb = (const float*)d_in[8];
  const float* Wlb = (const float*)d_in[9];
  const float* blb = (const float*)d_in[10];
  const float* onw = (const float*)d_in[11];
  const float* onb = (const float*)d_in[12];
  const float* Wgo = (const float*)d_in[13];
  const float* bgo = (const float*)d_in[14];
  const float* Wlo = (const float*)d_in[15];
  const float* blo = (const float*)d_in[16];

  u16* ws   = (u16*)d_ws;
  u16* wt   = ws + WT_OFF;
  float* b2 = (float*)(ws + B2_OFF);
  float* out = (float*)d_out;

  conv_kernel<<<387, 256, 0, stream>>>(Wga, Wla, Wgb, Wlb, Wgo, Wlo,
                                       lnw, lnb, onw, onb,
                                       bga, bla, bgb, blb, bgo, blo, wt, b2);

  if (ws_size >= WS2_NEED_BYTES){
    u16* zn_g = ws + ZN_OFF;
    u16* a_t  = ws + AT2_OFF;
    u16* b_tt = ws + BT2_OFF;
    u16* k_t  = ws + KT2_OFF;
    stageZ_kernel<<<2048, 256, 0, stream>>>(z, zn_g);
    stageA2_kernel<<<4096, 256, 0, stream>>>(zn_g, wt, b2, a_t, b_tt);
    stageT_kernel<<<2048, 256, 0, stream>>>(a_t, b_tt, k_t);
    stageC2_kernel<<<4096, 256, 0, stream>>>(k_t, zn_g, wt, b2, out);
  } else {
    u16* a_t  = ws + AT1_OFF;
    u16* b_tt = ws + BT1_OFF;
    u16* k_t  = ws + KT1_OFF;
    stageA_kernel<<<4096, 256, 0, stream>>>(z, wt, b2, a_t, b_tt);
    stageT_kernel<<<2048, 256, 0, stream>>>(a_t, b_tt, k_t);
    stageC_kernel<<<4096, 256, 0, stream>>>(k_t, z, wt, b2, out);
  }
}